// Round 2
// baseline (3468.500 us; speedup 1.0000x reference)
//
#include <hip/hip_runtime.h>

// Problem constants
#define Bn 4
#define Nn 8192
#define Dn 64
#define Sn 2048
#define Kn 32
#define R2c 0.04f          // f32(0.2*0.2)
#define OUT_XYZ (Bn*Sn*3)  // 24576 floats of new_xyz, then feats

// Workspace layout (units = 4-byte elements)
#define WS_P4  0            // [B*N] float4 {x,y,z,0}
#define WS_WB1 131072       // bf16 W1' [64][96]  (feat-first permute, zero pad)
#define WS_WB2 134144       // bf16 W2  [128][64]
#define WS_WB3 138240       // bf16 W3  [256][128]
#define WS_GRP 154624       // int grp_idx [B*S][K]

#define HSTR 136            // bf16 LDS row stride (128 max C + 8 pad)

typedef __attribute__((ext_vector_type(8))) short short8;
typedef __attribute__((ext_vector_type(4))) float floatx4;
typedef __attribute__((ext_vector_type(2))) float float2v;

// float -> bf16 (RNE) without relying on header APIs
__device__ __forceinline__ unsigned short f2bf(float f) {
    unsigned u = __float_as_uint(f);
    return (unsigned short)((u + 0x7FFFu + ((u >> 16) & 1u)) >> 16);
}

// ---------------------------------------------------------------------------
// Prep: xyz -> float4 array; weights -> bf16 [O][Cp] row-major.
// ---------------------------------------------------------------------------
__global__ __launch_bounds__(256) void prep_kernel(const float* __restrict__ xyz,
                                                   const float* __restrict__ W1,
                                                   const float* __restrict__ W2,
                                                   const float* __restrict__ W3,
                                                   float* __restrict__ ws) {
    int id = blockIdx.x * 256 + threadIdx.x;
    if (id < Bn * Nn) {
        float4* p4 = (float4*)(ws + WS_P4);
        p4[id] = make_float4(xyz[id * 3 + 0], xyz[id * 3 + 1], xyz[id * 3 + 2], 0.f);
    }
    int i1 = id - Bn * Nn;
    if (i1 >= 0 && i1 < 64 * 96) {
        int o = i1 / 96, c = i1 % 96;
        float v = (c < 64) ? W1[o * 67 + 3 + c] : (c < 67 ? W1[o * 67 + (c - 64)] : 0.f);
        ((unsigned short*)(ws + WS_WB1))[i1] = f2bf(v);
    }
    int i2 = i1 - 64 * 96;
    if (i2 >= 0 && i2 < 128 * 64)
        ((unsigned short*)(ws + WS_WB2))[i2] = f2bf(W2[i2]);
    int i3 = i2 - 128 * 64;
    if (i3 >= 0 && i3 < 256 * 128)
        ((unsigned short*)(ws + WS_WB3))[i3] = f2bf(W3[i3]);
}

// DPP wave-64 max (VALU pipe); lane 63 holds full-wave max, broadcast via readlane.
__device__ __forceinline__ float wave_fmax_dpp(float x) {
    float t;
    t = __int_as_float(__builtin_amdgcn_update_dpp(0, __float_as_int(x), 0x111, 0xf, 0xf, true)); x = fmaxf(x, t);
    t = __int_as_float(__builtin_amdgcn_update_dpp(0, __float_as_int(x), 0x112, 0xf, 0xf, true)); x = fmaxf(x, t);
    t = __int_as_float(__builtin_amdgcn_update_dpp(0, __float_as_int(x), 0x114, 0xf, 0xf, true)); x = fmaxf(x, t);
    t = __int_as_float(__builtin_amdgcn_update_dpp(0, __float_as_int(x), 0x118, 0xf, 0xf, true)); x = fmaxf(x, t);
    t = __int_as_float(__builtin_amdgcn_update_dpp(0, __float_as_int(x), 0x142, 0xf, 0xf, true)); x = fmaxf(x, t);
    t = __int_as_float(__builtin_amdgcn_update_dpp(0, __float_as_int(x), 0x143, 0xf, 0xf, true)); x = fmaxf(x, t);
    return __int_as_float(__builtin_amdgcn_readlane(__float_as_int(x), 63));
}

// DPP wave-64 unsigned max (branchless index reduce). bound_ctrl injects 0,
// which is the identity for umax. Returns SGPR-uniform result.
__device__ __forceinline__ unsigned wave_umax_dpp(unsigned x) {
    unsigned t;
    t = (unsigned)__builtin_amdgcn_update_dpp(0, (int)x, 0x111, 0xf, 0xf, true); x = (t > x) ? t : x;
    t = (unsigned)__builtin_amdgcn_update_dpp(0, (int)x, 0x112, 0xf, 0xf, true); x = (t > x) ? t : x;
    t = (unsigned)__builtin_amdgcn_update_dpp(0, (int)x, 0x114, 0xf, 0xf, true); x = (t > x) ? t : x;
    t = (unsigned)__builtin_amdgcn_update_dpp(0, (int)x, 0x118, 0xf, 0xf, true); x = (t > x) ? t : x;
    t = (unsigned)__builtin_amdgcn_update_dpp(0, (int)x, 0x142, 0xf, 0xf, true); x = (t > x) ? t : x;
    t = (unsigned)__builtin_amdgcn_update_dpp(0, (int)x, 0x143, 0xf, 0xf, true); x = (t > x) ? t : x;
    return (unsigned)__builtin_amdgcn_readlane((int)x, 63);
}

// 64-bit key + coord payload reduce: keep (kb,xb,yb,zb) if kb > ka.
#define RED8(ka, xa, ya, za, kb, xb, yb, zb)       \
    {                                              \
        bool t_ = (kb) > (ka);                     \
        ka = t_ ? (kb) : (ka);                     \
        xa = t_ ? (xb) : (xa);                     \
        ya = t_ ? (yb) : (ya);                     \
        za = t_ ? (zb) : (za);                     \
    }

// ---------------------------------------------------------------------------
// Farthest point sampling — serial-tail rework of the R1 config.
// 512 thr x 16 pts (8 point-pairs per thread), ONE barrier/step.
// Changes vs R1 (2190 us):
//  * winner COORDS carried through the reduction — the per-step post-barrier
//    L2/scalar fetch p4[winner] (~200-250 cy on the serial chain) is gone.
//    The wave-winner index is SGPR-uniform after the umax ladder, so an
//    8-case uniform scalar branch extracts the winning point's coords from
//    the register file; the winning lane writes (key,x,y,z) to LDS; the
//    post-barrier tree reduces keys WITH coord payload (cmp_u64 + 5 cndmask
//    per rung). Next centroid comes straight out of the tree.
//  * recovery chain -> binary tree: per-point candidate complement
//    (match ? ~idx : 0), 15-op umax tree (depth 4 vs 16-deep cndmask chain).
// Tie/first-occurrence semantics identical: key = (dist_bits<<32) | ~idx,
// max over keys == (max dist, min idx) since dists >= 0.
// ---------------------------------------------------------------------------
__global__ __launch_bounds__(512, 2) void fps_kernel(const float* __restrict__ ws,
                                                     float* __restrict__ out_xyz) {
    #pragma clang fp contract(off)
    const int b = blockIdx.x;
    const int tid = threadIdx.x;
    const float4* p4 = (const float4*)(ws + WS_P4) + b * Nn;

    // pair u holds points j=2u (.x) and j=2u+1 (.y); global idx = j*512 + tid
    float2v pX[8], pY[8], pZ[8], dI[8];
    #pragma unroll
    for (int u = 0; u < 8; u++) {
        float4 va = p4[(2 * u) * 512 + tid];
        float4 vb = p4[(2 * u + 1) * 512 + tid];
        pX[u].x = va.x; pX[u].y = vb.x;
        pY[u].x = va.y; pY[u].y = vb.y;
        pZ[u].x = va.z; pZ[u].y = vb.z;
        dI[u].x = 1e10f; dI[u].y = 1e10f;
    }
    #pragma unroll
    for (int u = 0; u < 8; u++) {
        asm volatile("" : "+v"(pX[u]), "+v"(pY[u]), "+v"(pZ[u]), "+v"(dI[u]));
    }

    __shared__ unsigned long long sKey[2][8];
    __shared__ float4 sCrd[2][8];
    __shared__ float sHist[Sn * 3];

    float4 c0 = p4[0];
    float cx = c0.x, cy = c0.y, cz = c0.z;

    for (int s = 0; s < Sn; s++) {
        const int par = s & 1;
        if (tid == 0) {
            sHist[s * 3 + 0] = cx;
            sHist[s * 3 + 1] = cy;
            sHist[s * 3 + 2] = cz;
        }
        // broadcast negated centroid into packed operands (p - c == p + (-c), exact)
        float nxs = -cx, nys = -cy, nzs = -cz;
        float2v nX, nY, nZ;
        nX.x = nxs; nX.y = nxs;
        nY.x = nys; nY.y = nys;
        nZ.x = nzs; nZ.y = nzs;

        float lv = -1.0f;
        #pragma unroll
        for (int u = 0; u < 8; u++) {
            float2v dx, dy, dz, xx, yy, zz, s1, d2;
            asm("v_pk_add_f32 %0, %1, %2" : "=v"(dx) : "v"(pX[u]), "v"(nX));
            asm("v_pk_add_f32 %0, %1, %2" : "=v"(dy) : "v"(pY[u]), "v"(nY));
            asm("v_pk_add_f32 %0, %1, %2" : "=v"(dz) : "v"(pZ[u]), "v"(nZ));
            asm("v_pk_mul_f32 %0, %1, %1" : "=v"(xx) : "v"(dx));
            asm("v_pk_mul_f32 %0, %1, %1" : "=v"(yy) : "v"(dy));
            asm("v_pk_mul_f32 %0, %1, %1" : "=v"(zz) : "v"(dz));
            asm("v_pk_add_f32 %0, %1, %2" : "=v"(s1) : "v"(xx), "v"(yy));
            asm("v_pk_add_f32 %0, %1, %2" : "=v"(d2) : "v"(s1), "v"(zz));
            float mx = fminf(dI[u].x, d2.x);
            float my = fminf(dI[u].y, d2.y);
            dI[u].x = mx; dI[u].y = my;
            lv = fmaxf(fmaxf(lv, mx), my);   // fuses to v_max3_f32
        }
        float wmax = wave_fmax_dpp(lv);

        // per-point candidate complements (match ? ~idx : 0), binary umax tree
        unsigned c[16];
        #pragma unroll
        for (int u = 0; u < 8; u++) {
            c[2 * u]     = (dI[u].x == wmax) ? (0xFFFFFFFFu - (unsigned)((2 * u) * 512 + tid)) : 0u;
            c[2 * u + 1] = (dI[u].y == wmax) ? (0xFFFFFFFFu - (unsigned)((2 * u + 1) * 512 + tid)) : 0u;
        }
        #pragma unroll
        for (int st = 1; st < 16; st <<= 1)
            #pragma unroll
            for (int i = 0; i < 16; i += 2 * st)
                c[i] = (c[i + st] > c[i]) ? c[i + st] : c[i];
        unsigned best = wave_umax_dpp(c[0]);   // SGPR-uniform

        // wave-winner index is uniform: extract its coords via uniform branch
        int pbw = (int)(0xFFFFFFFFu - best);   // j*512 + tid_win
        int jj = pbw >> 9;                     // 0..15
        int uu = jj >> 1, hf = jj & 1;         // pair, half (uniform scalars)
        float wx = 0.f, wy = 0.f, wz = 0.f;
        #pragma unroll
        for (int q = 0; q < 8; q++) {
            if (uu == q) {                     // uniform scalar branch
                wx = hf ? pX[q].y : pX[q].x;
                wy = hf ? pY[q].y : pY[q].x;
                wz = hf ? pZ[q].y : pZ[q].x;
            }
        }
        if (tid == (pbw & 511)) {              // exactly the winning lane
            sKey[par][tid >> 6] =
                ((unsigned long long)__float_as_uint(wmax) << 32) |
                (unsigned long long)best;
            sCrd[par][tid >> 6] = make_float4(wx, wy, wz, 0.f);
        }
        __syncthreads();

        // cross-wave tree with coord payload — no post-barrier memory fetch
        unsigned long long k0 = sKey[par][0], k1 = sKey[par][1];
        unsigned long long k2 = sKey[par][2], k3 = sKey[par][3];
        unsigned long long k4 = sKey[par][4], k5 = sKey[par][5];
        unsigned long long k6 = sKey[par][6], k7 = sKey[par][7];
        float4 q0 = sCrd[par][0], q1 = sCrd[par][1];
        float4 q2 = sCrd[par][2], q3 = sCrd[par][3];
        float4 q4 = sCrd[par][4], q5 = sCrd[par][5];
        float4 q6 = sCrd[par][6], q7 = sCrd[par][7];
        RED8(k0, q0.x, q0.y, q0.z, k1, q1.x, q1.y, q1.z);
        RED8(k2, q2.x, q2.y, q2.z, k3, q3.x, q3.y, q3.z);
        RED8(k4, q4.x, q4.y, q4.z, k5, q5.x, q5.y, q5.z);
        RED8(k6, q6.x, q6.y, q6.z, k7, q7.x, q7.y, q7.z);
        RED8(k0, q0.x, q0.y, q0.z, k2, q2.x, q2.y, q2.z);
        RED8(k4, q4.x, q4.y, q4.z, k6, q6.x, q6.y, q6.z);
        RED8(k0, q0.x, q0.y, q0.z, k4, q4.x, q4.y, q4.z);
        cx = q0.x; cy = q0.y; cz = q0.z;
    }

    __syncthreads();
    float4* o4 = (float4*)(out_xyz + b * Sn * 3);
    const float4* h4 = (const float4*)sHist;
    #pragma unroll
    for (int i = tid; i < Sn * 3 / 4; i += 512) o4[i] = h4[i];
}

// ---------------------------------------------------------------------------
// Ball query (unchanged; exact-decision verified: absmax 0.0).
// ---------------------------------------------------------------------------
__global__ __launch_bounds__(256) void ballq_kernel(const float* __restrict__ ws,
                                                    const float* __restrict__ newxyz,
                                                    int* __restrict__ grp) {
    #pragma clang fp contract(off)
    int t = blockIdx.x * 256 + threadIdx.x;
    int wid = t >> 6;
    int lane = t & 63;
    int b = wid >> 11;
    const float4* p4 = (const float4*)(ws + WS_P4) + b * Nn;

    float nx = newxyz[wid * 3 + 0], ny = newxyz[wid * 3 + 1], nz = newxyz[wid * 3 + 2];
    float a2 = (nx * nx + ny * ny) + nz * nz;

    int total = 0;
    int firstp = 0;
    for (int c = 0; c < Nn / 64; c++) {
        int p = c * 64 + lane;
        float4 v = p4[p];
        float x = v.x, y = v.y, z = v.z;
        float bv = (x * x + y * y) + z * z;
        float dot = __builtin_fmaf(nx, x, 0.0f);
        dot = __builtin_fmaf(ny, y, dot);
        dot = __builtin_fmaf(nz, z, dot);
        float sq = (a2 + bv) - 2.0f * dot;
        bool hit = !(sq > R2c);
        unsigned long long mask = __ballot(hit);
        if (mask) {
            if (total == 0) firstp = c * 64 + (__ffsll(mask) - 1);
            int rank = __popcll(mask & ((1ull << lane) - 1ull));
            int slot = total + rank;
            if (hit && slot < Kn) grp[wid * Kn + slot] = p;
            total += (int)__popcll(mask);
            if (total >= Kn) break;
        }
    }
    if (lane >= total && lane < Kn) grp[wid * Kn + lane] = firstp;
}

// ---------------------------------------------------------------------------
// MFMA MLP (unchanged): one group per block, 256 threads = 4 waves.
// ---------------------------------------------------------------------------
template<int KB, int O>
__device__ __forceinline__ void mfma_layer(const unsigned short* __restrict__ X,
                                           unsigned short* __restrict__ Y,
                                           const unsigned short* __restrict__ wb,
                                           const float* __restrict__ bias,
                                           int lane, int wv) {
    const int Cp = KB * 32;
    const int mt = wv & 1;
    const int mrow = mt * 16 + (lane & 15);
    const int quad = lane >> 4;

    short8 a[KB];
    #pragma unroll
    for (int kb = 0; kb < KB; kb++)
        a[kb] = *(const short8*)&X[mrow * HSTR + kb * 32 + quad * 8];

    for (int nt = (wv >> 1); nt < O / 16; nt += 2) {
        int n0 = nt * 16;
        float bv = bias[n0 + (lane & 15)];
        floatx4 acc = {bv, bv, bv, bv};
        #pragma unroll
        for (int kb = 0; kb < KB; kb++) {
            short8 bf = *(const short8*)&wb[(n0 + (lane & 15)) * Cp + kb * 32 + quad * 8];
            acc = __builtin_amdgcn_mfma_f32_16x16x32_bf16(a[kb], bf, acc, 0, 0, 0);
        }
        #pragma unroll
        for (int r = 0; r < 4; r++) {
            float v = fmaxf(acc[r], 0.f);
            int m = mt * 16 + quad * 4 + r;
            Y[m * HSTR + n0 + (lane & 15)] = f2bf(v);
        }
    }
}

__global__ __launch_bounds__(256) void mlp_kernel(const float* __restrict__ xyz,
                                                  const float* __restrict__ feat,
                                                  const float* __restrict__ ws,
                                                  const int* __restrict__ grp,
                                                  const float* __restrict__ b1,
                                                  const float* __restrict__ b2,
                                                  const float* __restrict__ b3,
                                                  float* __restrict__ out) {
    __shared__ __align__(16) unsigned short hA[32 * HSTR];
    __shared__ __align__(16) unsigned short hB[32 * HSTR];
    __shared__ float mxs[2][256];
    __shared__ int   sIdx[Kn];
    __shared__ float sCent[3];

    int g = blockIdx.x;            // b*S + s
    int b = g >> 11;
    int tid = threadIdx.x;
    int lane = tid & 63, wv = tid >> 6;

    if (tid < Kn) sIdx[tid] = grp[g * Kn + tid];
    if (tid == 0) { sCent[0] = out[g*3]; sCent[1] = out[g*3+1]; sCent[2] = out[g*3+2]; }
    // zero hA (pad cols must be 0 for the K=96 layer)
    {
        short8 z = {0,0,0,0,0,0,0,0};
        for (int i = tid; i < 32 * HSTR / 8; i += 256)
            ((short8*)hA)[i] = z;
    }
    __syncthreads();

    { // stage h0: feats -> cols 0..63 (bf16x8 vector writes), xyz -> 64..66
        int m = tid >> 3, m8 = tid & 7;
        int idx = sIdx[m];
        int base = b * Nn + idx;
        const float4* f4 = (const float4*)(feat + base * 64 + m8 * 8);
        float4 va = f4[0], vb = f4[1];
        short8 pk;
        pk[0] = (short)f2bf(va.x); pk[1] = (short)f2bf(va.y);
        pk[2] = (short)f2bf(va.z); pk[3] = (short)f2bf(va.w);
        pk[4] = (short)f2bf(vb.x); pk[5] = (short)f2bf(vb.y);
        pk[6] = (short)f2bf(vb.z); pk[7] = (short)f2bf(vb.w);
        *(short8*)&hA[m * HSTR + m8 * 8] = pk;
        if (m8 == 0) {
            hA[m * HSTR + 64] = f2bf(xyz[base * 3 + 0] - sCent[0]);
            hA[m * HSTR + 65] = f2bf(xyz[base * 3 + 1] - sCent[1]);
            hA[m * HSTR + 66] = f2bf(xyz[base * 3 + 2] - sCent[2]);
        }
    }
    __syncthreads();

    const unsigned short* wb1 = (const unsigned short*)(ws + WS_WB1);
    const unsigned short* wb2 = (const unsigned short*)(ws + WS_WB2);
    const unsigned short* wb3 = (const unsigned short*)(ws + WS_WB3);

    mfma_layer<3, 64>(hA, hB, wb1, b1, lane, wv);     // 96 -> 64
    __syncthreads();
    mfma_layer<2, 128>(hB, hA, wb2, b2, lane, wv);    // 64 -> 128
    __syncthreads();

    { // L3 (128 -> 256) + fused maxpool
        const int mt = wv & 1;
        const int mrow = mt * 16 + (lane & 15);
        const int quad = lane >> 4;
        short8 a[4];
        #pragma unroll
        for (int kb = 0; kb < 4; kb++)
            a[kb] = *(const short8*)&hA[mrow * HSTR + kb * 32 + quad * 8];
        for (int nt = (wv >> 1); nt < 16; nt += 2) {
            int n0 = nt * 16;
            float bv = b3[n0 + (lane & 15)];
            floatx4 acc = {bv, bv, bv, bv};
            #pragma unroll
            for (int kb = 0; kb < 4; kb++) {
                short8 bf = *(const short8*)&wb3[(n0 + (lane & 15)) * 128 + kb * 32 + quad * 8];
                acc = __builtin_amdgcn_mfma_f32_16x16x32_bf16(a[kb], bf, acc, 0, 0, 0);
            }
            float pm = fmaxf(fmaxf(fmaxf(acc[0], acc[1]), fmaxf(acc[2], acc[3])), 0.f);
            pm = fmaxf(pm, __shfl_xor(pm, 16));   // reduce across the 4 quads
            pm = fmaxf(pm, __shfl_xor(pm, 32));
            if (lane < 16) mxs[mt][n0 + lane] = pm;
        }
    }
    __syncthreads();

    out[OUT_XYZ + g * 256 + tid] = fmaxf(mxs[0][tid], mxs[1][tid]);
}

// ---------------------------------------------------------------------------
extern "C" void kernel_launch(void* const* d_in, const int* in_sizes, int n_in,
                              void* d_out, int out_size, void* d_ws, size_t ws_size,
                              hipStream_t stream) {
    const float* xyz  = (const float*)d_in[0];
    const float* feat = (const float*)d_in[1];
    const float* W1   = (const float*)d_in[2];
    const float* b1   = (const float*)d_in[3];
    const float* W2   = (const float*)d_in[4];
    const float* b2   = (const float*)d_in[5];
    const float* W3   = (const float*)d_in[6];
    const float* b3   = (const float*)d_in[7];
    float* out = (float*)d_out;
    float* ws  = (float*)d_ws;
    int*   grp = (int*)d_ws + WS_GRP;

    hipLaunchKernelGGL(prep_kernel, dim3(312), dim3(256), 0, stream, xyz, W1, W2, W3, ws);
    hipLaunchKernelGGL(fps_kernel, dim3(Bn), dim3(512), 0, stream, ws, out);
    hipLaunchKernelGGL(ballq_kernel, dim3(Bn * Sn / 4), dim3(256), 0, stream, ws, out, grp);
    hipLaunchKernelGGL(mlp_kernel, dim3(Bn * Sn), dim3(256), 0, stream,
                       xyz, feat, ws, grp, b1, b2, b3, out);
}

// Round 3
// 2451.992 us; speedup vs baseline: 1.4146x; 1.4146x over previous
//
#include <hip/hip_runtime.h>

// Problem constants
#define Bn 4
#define Nn 8192
#define Dn 64
#define Sn 2048
#define Kn 32
#define R2c 0.04f          // f32(0.2*0.2)
#define OUT_XYZ (Bn*Sn*3)  // 24576 floats of new_xyz, then feats

// Workspace layout (units = 4-byte elements)
#define WS_P4  0            // [B*N] float4 {x,y,z,0}
#define WS_WB1 131072       // bf16 W1' [64][96]  (feat-first permute, zero pad)
#define WS_WB2 134144       // bf16 W2  [128][64]
#define WS_WB3 138240       // bf16 W3  [256][128]
#define WS_GRP 154624       // int grp_idx [B*S][K]

#define HSTR 136            // bf16 LDS row stride (128 max C + 8 pad)

typedef __attribute__((ext_vector_type(8))) short short8;
typedef __attribute__((ext_vector_type(4))) float floatx4;
typedef __attribute__((ext_vector_type(2))) float float2v;

// float -> bf16 (RNE) without relying on header APIs
__device__ __forceinline__ unsigned short f2bf(float f) {
    unsigned u = __float_as_uint(f);
    return (unsigned short)((u + 0x7FFFu + ((u >> 16) & 1u)) >> 16);
}

// ---------------------------------------------------------------------------
// Prep: xyz -> float4 array; weights -> bf16 [O][Cp] row-major.
// ---------------------------------------------------------------------------
__global__ __launch_bounds__(256) void prep_kernel(const float* __restrict__ xyz,
                                                   const float* __restrict__ W1,
                                                   const float* __restrict__ W2,
                                                   const float* __restrict__ W3,
                                                   float* __restrict__ ws) {
    int id = blockIdx.x * 256 + threadIdx.x;
    if (id < Bn * Nn) {
        float4* p4 = (float4*)(ws + WS_P4);
        p4[id] = make_float4(xyz[id * 3 + 0], xyz[id * 3 + 1], xyz[id * 3 + 2], 0.f);
    }
    int i1 = id - Bn * Nn;
    if (i1 >= 0 && i1 < 64 * 96) {
        int o = i1 / 96, c = i1 % 96;
        float v = (c < 64) ? W1[o * 67 + 3 + c] : (c < 67 ? W1[o * 67 + (c - 64)] : 0.f);
        ((unsigned short*)(ws + WS_WB1))[i1] = f2bf(v);
    }
    int i2 = i1 - 64 * 96;
    if (i2 >= 0 && i2 < 128 * 64)
        ((unsigned short*)(ws + WS_WB2))[i2] = f2bf(W2[i2]);
    int i3 = i2 - 128 * 64;
    if (i3 >= 0 && i3 < 256 * 128)
        ((unsigned short*)(ws + WS_WB3))[i3] = f2bf(W3[i3]);
}

// DPP wave-64 max (VALU pipe); lane 63 holds full-wave max, broadcast via readlane.
__device__ __forceinline__ float wave_fmax_dpp(float x) {
    float t;
    t = __int_as_float(__builtin_amdgcn_update_dpp(0, __float_as_int(x), 0x111, 0xf, 0xf, true)); x = fmaxf(x, t);
    t = __int_as_float(__builtin_amdgcn_update_dpp(0, __float_as_int(x), 0x112, 0xf, 0xf, true)); x = fmaxf(x, t);
    t = __int_as_float(__builtin_amdgcn_update_dpp(0, __float_as_int(x), 0x114, 0xf, 0xf, true)); x = fmaxf(x, t);
    t = __int_as_float(__builtin_amdgcn_update_dpp(0, __float_as_int(x), 0x118, 0xf, 0xf, true)); x = fmaxf(x, t);
    t = __int_as_float(__builtin_amdgcn_update_dpp(0, __float_as_int(x), 0x142, 0xf, 0xf, true)); x = fmaxf(x, t);
    t = __int_as_float(__builtin_amdgcn_update_dpp(0, __float_as_int(x), 0x143, 0xf, 0xf, true)); x = fmaxf(x, t);
    return __int_as_float(__builtin_amdgcn_readlane(__float_as_int(x), 63));
}

// DPP wave-64 unsigned max (branchless index reduce). bound_ctrl injects 0,
// which is the identity for umax. Returns SGPR-uniform result.
__device__ __forceinline__ unsigned wave_umax_dpp(unsigned x) {
    unsigned t;
    t = (unsigned)__builtin_amdgcn_update_dpp(0, (int)x, 0x111, 0xf, 0xf, true); x = (t > x) ? t : x;
    t = (unsigned)__builtin_amdgcn_update_dpp(0, (int)x, 0x112, 0xf, 0xf, true); x = (t > x) ? t : x;
    t = (unsigned)__builtin_amdgcn_update_dpp(0, (int)x, 0x114, 0xf, 0xf, true); x = (t > x) ? t : x;
    t = (unsigned)__builtin_amdgcn_update_dpp(0, (int)x, 0x118, 0xf, 0xf, true); x = (t > x) ? t : x;
    t = (unsigned)__builtin_amdgcn_update_dpp(0, (int)x, 0x142, 0xf, 0xf, true); x = (t > x) ? t : x;
    t = (unsigned)__builtin_amdgcn_update_dpp(0, (int)x, 0x143, 0xf, 0xf, true); x = (t > x) ? t : x;
    return (unsigned)__builtin_amdgcn_readlane((int)x, 63);
}

// ---------------------------------------------------------------------------
// Farthest point sampling — R1 structure + register-residency fix.
// 512 thr x 16 pts (8 point-pairs per thread), ONE barrier/step.
//
// KEY FIX vs R1 (2190 us): R1's VGPR_Count=48 cannot hold the 48 VGPRs of
// pX/pY/pZ pairs + dI + temps -> the compiler was REMATERIALIZING the
// loop-invariant p4[] loads (legal under __restrict__) by re-reading all
// 16 float4/thread from L2 EVERY STEP (~128KB/step/CU ~ 2000 cy/step of L2
// BW -- the unexplained gap between the ~850-cy issue/latency model and the
// measured 2570 cy/step; invisible in FETCH_SIZE because the point set is
// L2-resident). The keep-alive asm now sits INSIDE the s-loop, making the
// pairs loop-carried: the compiler must keep them register-resident
// (budget 256 VGPR at 2 waves/SIMD -- no scratch).
//
// Also: recovery chain (16-deep cndmask) -> 4-deep binary umax tree over
// candidate complements (match ? ~idx : 0). Identical instruction count &
// tie semantics (max of complements == min idx == smallest j), shorter
// dependence chain.
// ---------------------------------------------------------------------------
__global__ __launch_bounds__(512, 2) void fps_kernel(const float* __restrict__ ws,
                                                     float* __restrict__ out_xyz) {
    #pragma clang fp contract(off)
    const int b = blockIdx.x;
    const int tid = threadIdx.x;
    const float4* p4 = (const float4*)(ws + WS_P4) + b * Nn;

    // pair u holds points j=2u (.x) and j=2u+1 (.y); global idx = j*512 + tid
    float2v pX[8], pY[8], pZ[8], dI[8];
    #pragma unroll
    for (int u = 0; u < 8; u++) {
        float4 va = p4[(2 * u) * 512 + tid];
        float4 vb = p4[(2 * u + 1) * 512 + tid];
        pX[u].x = va.x; pX[u].y = vb.x;
        pY[u].x = va.y; pY[u].y = vb.y;
        pZ[u].x = va.z; pZ[u].y = vb.z;
        dI[u].x = 1e10f; dI[u].y = 1e10f;
    }

    __shared__ unsigned long long sKey[2][8];
    __shared__ float sHist[Sn * 3];

    float4 c0 = p4[0];
    float cx = c0.x, cy = c0.y, cz = c0.z;

    for (int s = 0; s < Sn; s++) {
        // Register-residency pin: mark the point pairs as (potentially)
        // modified each iteration -> no remat-by-reload from p4, values
        // stay in VGPRs across the whole loop.
        #pragma unroll
        for (int u = 0; u < 8; u++) {
            asm volatile("" : "+v"(pX[u]), "+v"(pY[u]), "+v"(pZ[u]));
        }

        const int par = s & 1;
        if (tid == 0) {
            sHist[s * 3 + 0] = cx;
            sHist[s * 3 + 1] = cy;
            sHist[s * 3 + 2] = cz;
        }
        // broadcast negated centroid into packed operands (p - c == p + (-c), exact)
        float nxs = -cx, nys = -cy, nzs = -cz;
        float2v nX, nY, nZ;
        nX.x = nxs; nX.y = nxs;
        nY.x = nys; nY.y = nys;
        nZ.x = nzs; nZ.y = nzs;

        float lv = -1.0f;
        #pragma unroll
        for (int u = 0; u < 8; u++) {
            float2v dx, dy, dz, xx, yy, zz, s1, d2;
            asm("v_pk_add_f32 %0, %1, %2" : "=v"(dx) : "v"(pX[u]), "v"(nX));
            asm("v_pk_add_f32 %0, %1, %2" : "=v"(dy) : "v"(pY[u]), "v"(nY));
            asm("v_pk_add_f32 %0, %1, %2" : "=v"(dz) : "v"(pZ[u]), "v"(nZ));
            asm("v_pk_mul_f32 %0, %1, %1" : "=v"(xx) : "v"(dx));
            asm("v_pk_mul_f32 %0, %1, %1" : "=v"(yy) : "v"(dy));
            asm("v_pk_mul_f32 %0, %1, %1" : "=v"(zz) : "v"(dz));
            asm("v_pk_add_f32 %0, %1, %2" : "=v"(s1) : "v"(xx), "v"(yy));
            asm("v_pk_add_f32 %0, %1, %2" : "=v"(d2) : "v"(s1), "v"(zz));
            float mx = fminf(dI[u].x, d2.x);
            float my = fminf(dI[u].y, d2.y);
            dI[u].x = mx; dI[u].y = my;
            lv = fmaxf(fmaxf(lv, mx), my);   // fuses to v_max3_f32
        }
        float wmax = wave_fmax_dpp(lv);

        // per-point candidate complements (match ? ~idx : 0), binary umax tree
        unsigned c[16];
        #pragma unroll
        for (int u = 0; u < 8; u++) {
            c[2 * u]     = (dI[u].x == wmax) ? (0xFFFFFFFFu - (unsigned)((2 * u) * 512 + tid)) : 0u;
            c[2 * u + 1] = (dI[u].y == wmax) ? (0xFFFFFFFFu - (unsigned)((2 * u + 1) * 512 + tid)) : 0u;
        }
        #pragma unroll
        for (int st = 1; st < 16; st <<= 1)
            #pragma unroll
            for (int i = 0; i < 16; i += 2 * st)
                c[i] = (c[i + st] > c[i]) ? c[i + st] : c[i];
        unsigned best = wave_umax_dpp(c[0]);   // SGPR-uniform

        if ((tid & 63) == 0) {
            sKey[par][tid >> 6] =
                ((unsigned long long)__float_as_uint(wmax) << 32) |
                (unsigned long long)best;
        }
        __syncthreads();
        unsigned long long a0 = sKey[par][0], a1 = sKey[par][1];
        unsigned long long a2 = sKey[par][2], a3 = sKey[par][3];
        unsigned long long a4 = sKey[par][4], a5 = sKey[par][5];
        unsigned long long a6 = sKey[par][6], a7 = sKey[par][7];
        a0 = (a1 > a0) ? a1 : a0;
        a2 = (a3 > a2) ? a3 : a2;
        a4 = (a5 > a4) ? a5 : a4;
        a6 = (a7 > a6) ? a7 : a6;
        a0 = (a2 > a0) ? a2 : a0;
        a4 = (a6 > a4) ? a6 : a4;
        unsigned long long k = (a4 > a0) ? a4 : a0;

        int p = (int)(0xFFFFFFFFu - (unsigned)(k & 0xFFFFFFFFull));
        p = __builtin_amdgcn_readfirstlane(p);
        float4 c4 = p4[p];
        cx = c4.x; cy = c4.y; cz = c4.z;
    }

    __syncthreads();
    float4* o4 = (float4*)(out_xyz + b * Sn * 3);
    const float4* h4 = (const float4*)sHist;
    #pragma unroll
    for (int i = tid; i < Sn * 3 / 4; i += 512) o4[i] = h4[i];
}

// ---------------------------------------------------------------------------
// Ball query (unchanged; exact-decision verified: absmax 0.0).
// ---------------------------------------------------------------------------
__global__ __launch_bounds__(256) void ballq_kernel(const float* __restrict__ ws,
                                                    const float* __restrict__ newxyz,
                                                    int* __restrict__ grp) {
    #pragma clang fp contract(off)
    int t = blockIdx.x * 256 + threadIdx.x;
    int wid = t >> 6;
    int lane = t & 63;
    int b = wid >> 11;
    const float4* p4 = (const float4*)(ws + WS_P4) + b * Nn;

    float nx = newxyz[wid * 3 + 0], ny = newxyz[wid * 3 + 1], nz = newxyz[wid * 3 + 2];
    float a2 = (nx * nx + ny * ny) + nz * nz;

    int total = 0;
    int firstp = 0;
    for (int c = 0; c < Nn / 64; c++) {
        int p = c * 64 + lane;
        float4 v = p4[p];
        float x = v.x, y = v.y, z = v.z;
        float bv = (x * x + y * y) + z * z;
        float dot = __builtin_fmaf(nx, x, 0.0f);
        dot = __builtin_fmaf(ny, y, dot);
        dot = __builtin_fmaf(nz, z, dot);
        float sq = (a2 + bv) - 2.0f * dot;
        bool hit = !(sq > R2c);
        unsigned long long mask = __ballot(hit);
        if (mask) {
            if (total == 0) firstp = c * 64 + (__ffsll(mask) - 1);
            int rank = __popcll(mask & ((1ull << lane) - 1ull));
            int slot = total + rank;
            if (hit && slot < Kn) grp[wid * Kn + slot] = p;
            total += (int)__popcll(mask);
            if (total >= Kn) break;
        }
    }
    if (lane >= total && lane < Kn) grp[wid * Kn + lane] = firstp;
}

// ---------------------------------------------------------------------------
// MFMA MLP (unchanged): one group per block, 256 threads = 4 waves.
// ---------------------------------------------------------------------------
template<int KB, int O>
__device__ __forceinline__ void mfma_layer(const unsigned short* __restrict__ X,
                                           unsigned short* __restrict__ Y,
                                           const unsigned short* __restrict__ wb,
                                           const float* __restrict__ bias,
                                           int lane, int wv) {
    const int Cp = KB * 32;
    const int mt = wv & 1;
    const int mrow = mt * 16 + (lane & 15);
    const int quad = lane >> 4;

    short8 a[KB];
    #pragma unroll
    for (int kb = 0; kb < KB; kb++)
        a[kb] = *(const short8*)&X[mrow * HSTR + kb * 32 + quad * 8];

    for (int nt = (wv >> 1); nt < O / 16; nt += 2) {
        int n0 = nt * 16;
        float bv = bias[n0 + (lane & 15)];
        floatx4 acc = {bv, bv, bv, bv};
        #pragma unroll
        for (int kb = 0; kb < KB; kb++) {
            short8 bf = *(const short8*)&wb[(n0 + (lane & 15)) * Cp + kb * 32 + quad * 8];
            acc = __builtin_amdgcn_mfma_f32_16x16x32_bf16(a[kb], bf, acc, 0, 0, 0);
        }
        #pragma unroll
        for (int r = 0; r < 4; r++) {
            float v = fmaxf(acc[r], 0.f);
            int m = mt * 16 + quad * 4 + r;
            Y[m * HSTR + n0 + (lane & 15)] = f2bf(v);
        }
    }
}

__global__ __launch_bounds__(256) void mlp_kernel(const float* __restrict__ xyz,
                                                  const float* __restrict__ feat,
                                                  const float* __restrict__ ws,
                                                  const int* __restrict__ grp,
                                                  const float* __restrict__ b1,
                                                  const float* __restrict__ b2,
                                                  const float* __restrict__ b3,
                                                  float* __restrict__ out) {
    __shared__ __align__(16) unsigned short hA[32 * HSTR];
    __shared__ __align__(16) unsigned short hB[32 * HSTR];
    __shared__ float mxs[2][256];
    __shared__ int   sIdx[Kn];
    __shared__ float sCent[3];

    int g = blockIdx.x;            // b*S + s
    int b = g >> 11;
    int tid = threadIdx.x;
    int lane = tid & 63, wv = tid >> 6;

    if (tid < Kn) sIdx[tid] = grp[g * Kn + tid];
    if (tid == 0) { sCent[0] = out[g*3]; sCent[1] = out[g*3+1]; sCent[2] = out[g*3+2]; }
    // zero hA (pad cols must be 0 for the K=96 layer)
    {
        short8 z = {0,0,0,0,0,0,0,0};
        for (int i = tid; i < 32 * HSTR / 8; i += 256)
            ((short8*)hA)[i] = z;
    }
    __syncthreads();

    { // stage h0: feats -> cols 0..63 (bf16x8 vector writes), xyz -> 64..66
        int m = tid >> 3, m8 = tid & 7;
        int idx = sIdx[m];
        int base = b * Nn + idx;
        const float4* f4 = (const float4*)(feat + base * 64 + m8 * 8);
        float4 va = f4[0], vb = f4[1];
        short8 pk;
        pk[0] = (short)f2bf(va.x); pk[1] = (short)f2bf(va.y);
        pk[2] = (short)f2bf(va.z); pk[3] = (short)f2bf(va.w);
        pk[4] = (short)f2bf(vb.x); pk[5] = (short)f2bf(vb.y);
        pk[6] = (short)f2bf(vb.z); pk[7] = (short)f2bf(vb.w);
        *(short8*)&hA[m * HSTR + m8 * 8] = pk;
        if (m8 == 0) {
            hA[m * HSTR + 64] = f2bf(xyz[base * 3 + 0] - sCent[0]);
            hA[m * HSTR + 65] = f2bf(xyz[base * 3 + 1] - sCent[1]);
            hA[m * HSTR + 66] = f2bf(xyz[base * 3 + 2] - sCent[2]);
        }
    }
    __syncthreads();

    const unsigned short* wb1 = (const unsigned short*)(ws + WS_WB1);
    const unsigned short* wb2 = (const unsigned short*)(ws + WS_WB2);
    const unsigned short* wb3 = (const unsigned short*)(ws + WS_WB3);

    mfma_layer<3, 64>(hA, hB, wb1, b1, lane, wv);     // 96 -> 64
    __syncthreads();
    mfma_layer<2, 128>(hB, hA, wb2, b2, lane, wv);    // 64 -> 128
    __syncthreads();

    { // L3 (128 -> 256) + fused maxpool
        const int mt = wv & 1;
        const int mrow = mt * 16 + (lane & 15);
        const int quad = lane >> 4;
        short8 a[4];
        #pragma unroll
        for (int kb = 0; kb < 4; kb++)
            a[kb] = *(const short8*)&hA[mrow * HSTR + kb * 32 + quad * 8];
        for (int nt = (wv >> 1); nt < 16; nt += 2) {
            int n0 = nt * 16;
            float bv = b3[n0 + (lane & 15)];
            floatx4 acc = {bv, bv, bv, bv};
            #pragma unroll
            for (int kb = 0; kb < 4; kb++) {
                short8 bf = *(const short8*)&wb3[(n0 + (lane & 15)) * 128 + kb * 32 + quad * 8];
                acc = __builtin_amdgcn_mfma_f32_16x16x32_bf16(a[kb], bf, acc, 0, 0, 0);
            }
            float pm = fmaxf(fmaxf(fmaxf(acc[0], acc[1]), fmaxf(acc[2], acc[3])), 0.f);
            pm = fmaxf(pm, __shfl_xor(pm, 16));   // reduce across the 4 quads
            pm = fmaxf(pm, __shfl_xor(pm, 32));
            if (lane < 16) mxs[mt][n0 + lane] = pm;
        }
    }
    __syncthreads();

    out[OUT_XYZ + g * 256 + tid] = fmaxf(mxs[0][tid], mxs[1][tid]);
}

// ---------------------------------------------------------------------------
extern "C" void kernel_launch(void* const* d_in, const int* in_sizes, int n_in,
                              void* d_out, int out_size, void* d_ws, size_t ws_size,
                              hipStream_t stream) {
    const float* xyz  = (const float*)d_in[0];
    const float* feat = (const float*)d_in[1];
    const float* W1   = (const float*)d_in[2];
    const float* b1   = (const float*)d_in[3];
    const float* W2   = (const float*)d_in[4];
    const float* b2   = (const float*)d_in[5];
    const float* W3   = (const float*)d_in[6];
    const float* b3   = (const float*)d_in[7];
    float* out = (float*)d_out;
    float* ws  = (float*)d_ws;
    int*   grp = (int*)d_ws + WS_GRP;

    hipLaunchKernelGGL(prep_kernel, dim3(312), dim3(256), 0, stream, xyz, W1, W2, W3, ws);
    hipLaunchKernelGGL(fps_kernel, dim3(Bn), dim3(512), 0, stream, ws, out);
    hipLaunchKernelGGL(ballq_kernel, dim3(Bn * Sn / 4), dim3(256), 0, stream, ws, out, grp);
    hipLaunchKernelGGL(mlp_kernel, dim3(Bn * Sn), dim3(256), 0, stream,
                       xyz, feat, ws, grp, b1, b2, b3, out);
}

// Round 4
// 1866.796 us; speedup vs baseline: 1.8580x; 1.3135x over previous
//
#include <hip/hip_runtime.h>

// Problem constants
#define Bn 4
#define Nn 8192
#define Dn 64
#define Sn 2048
#define Kn 32
#define R2c 0.04f          // f32(0.2*0.2)
#define OUT_XYZ (Bn*Sn*3)  // 24576 floats of new_xyz, then feats

// Workspace layout (units = 4-byte elements)
#define WS_P4  0            // [B*N] float4 {x,y,z,0}
#define WS_WB1 131072       // bf16 W1' [64][96]  (feat-first permute, zero pad)
#define WS_WB2 134144       // bf16 W2  [128][64]
#define WS_WB3 138240       // bf16 W3  [256][128]
#define WS_GRP 154624       // int grp_idx [B*S][K]

#define HSTR 136            // bf16 LDS row stride (128 max C + 8 pad)

typedef __attribute__((ext_vector_type(8))) short short8;
typedef __attribute__((ext_vector_type(4))) float floatx4;
typedef __attribute__((ext_vector_type(2))) float float2v;

// float -> bf16 (RNE) without relying on header APIs
__device__ __forceinline__ unsigned short f2bf(float f) {
    unsigned u = __float_as_uint(f);
    return (unsigned short)((u + 0x7FFFu + ((u >> 16) & 1u)) >> 16);
}

// ---------------------------------------------------------------------------
// Prep: xyz -> float4 array; weights -> bf16 [O][Cp] row-major.
// ---------------------------------------------------------------------------
__global__ __launch_bounds__(256) void prep_kernel(const float* __restrict__ xyz,
                                                   const float* __restrict__ W1,
                                                   const float* __restrict__ W2,
                                                   const float* __restrict__ W3,
                                                   float* __restrict__ ws) {
    int id = blockIdx.x * 256 + threadIdx.x;
    if (id < Bn * Nn) {
        float4* p4 = (float4*)(ws + WS_P4);
        p4[id] = make_float4(xyz[id * 3 + 0], xyz[id * 3 + 1], xyz[id * 3 + 2], 0.f);
    }
    int i1 = id - Bn * Nn;
    if (i1 >= 0 && i1 < 64 * 96) {
        int o = i1 / 96, c = i1 % 96;
        float v = (c < 64) ? W1[o * 67 + 3 + c] : (c < 67 ? W1[o * 67 + (c - 64)] : 0.f);
        ((unsigned short*)(ws + WS_WB1))[i1] = f2bf(v);
    }
    int i2 = i1 - 64 * 96;
    if (i2 >= 0 && i2 < 128 * 64)
        ((unsigned short*)(ws + WS_WB2))[i2] = f2bf(W2[i2]);
    int i3 = i2 - 128 * 64;
    if (i3 >= 0 && i3 < 256 * 128)
        ((unsigned short*)(ws + WS_WB3))[i3] = f2bf(W3[i3]);
}

// DPP wave-64 max (VALU pipe); lane 63 holds full-wave max, broadcast via readlane.
// bound_ctrl injects 0 into shifted-in lanes: identity-safe for max of
// NON-NEGATIVE values only (dists >= 0 ok).
__device__ __forceinline__ float wave_fmax_dpp(float x) {
    float t;
    t = __int_as_float(__builtin_amdgcn_update_dpp(0, __float_as_int(x), 0x111, 0xf, 0xf, true)); x = fmaxf(x, t);
    t = __int_as_float(__builtin_amdgcn_update_dpp(0, __float_as_int(x), 0x112, 0xf, 0xf, true)); x = fmaxf(x, t);
    t = __int_as_float(__builtin_amdgcn_update_dpp(0, __float_as_int(x), 0x114, 0xf, 0xf, true)); x = fmaxf(x, t);
    t = __int_as_float(__builtin_amdgcn_update_dpp(0, __float_as_int(x), 0x118, 0xf, 0xf, true)); x = fmaxf(x, t);
    t = __int_as_float(__builtin_amdgcn_update_dpp(0, __float_as_int(x), 0x142, 0xf, 0xf, true)); x = fmaxf(x, t);
    t = __int_as_float(__builtin_amdgcn_update_dpp(0, __float_as_int(x), 0x143, 0xf, 0xf, true)); x = fmaxf(x, t);
    return __int_as_float(__builtin_amdgcn_readlane(__float_as_int(x), 63));
}

// DPP wave-64 unsigned max (branchless index reduce). 0-injection = identity.
__device__ __forceinline__ unsigned wave_umax_dpp(unsigned x) {
    unsigned t;
    t = (unsigned)__builtin_amdgcn_update_dpp(0, (int)x, 0x111, 0xf, 0xf, true); x = (t > x) ? t : x;
    t = (unsigned)__builtin_amdgcn_update_dpp(0, (int)x, 0x112, 0xf, 0xf, true); x = (t > x) ? t : x;
    t = (unsigned)__builtin_amdgcn_update_dpp(0, (int)x, 0x114, 0xf, 0xf, true); x = (t > x) ? t : x;
    t = (unsigned)__builtin_amdgcn_update_dpp(0, (int)x, 0x118, 0xf, 0xf, true); x = (t > x) ? t : x;
    t = (unsigned)__builtin_amdgcn_update_dpp(0, (int)x, 0x142, 0xf, 0xf, true); x = (t > x) ? t : x;
    t = (unsigned)__builtin_amdgcn_update_dpp(0, (int)x, 0x143, 0xf, 0xf, true); x = (t > x) ? t : x;
    return (unsigned)__builtin_amdgcn_readlane((int)x, 63);
}

// ---------------------------------------------------------------------------
// Farthest point sampling — spatially-sorted wave-skip version.
//
// Structure: 512 thr (8 waves) x 16 pts/thread. Prologue z-sorts the 8192
// points (256-bin counting sort through a 32KB LDS staging buffer, 4 rounds)
// so wave w owns a contiguous z-slab of 1024 points, held in registers with
// ORIGINAL indices as payload. Per step, a wave whose slab is provably
// farther from the new centroid than its own current max dist SKIPS the
// entire distance update — its cached (wmax, ~origIdx) key stays valid
// because dists only decrease and min(dist,d)=dist for all its points.
//
// Exactness:
//  * skip test dz*dz*0.999999f >= wmaxC under-estimates the true min point
//    distance^2 by construction (covers bbox/square rounding, ~4ulp) ->
//    skip implies d >= dist[j] for every point -> update is identity ->
//    bit-identical trajectory.
//  * sorting is just a permutation; selection key carries ORIGINAL index
//    (~origIdx) so argmax first-occurrence tie-break and all outputs are
//    permutation-invariant. atomic-claim scatter guarantees a bijection.
//  * distance math unchanged from the verified pk-exact form
//    (add(x,-c), mul, (xx+yy)+zz), fmin/fmax scalar.
// Expected active waves/step ~1.5-2 after the first ~100 steps (covering
// radius < slab thickness) -> most waves idle at the barrier.
// ---------------------------------------------------------------------------
__global__ __launch_bounds__(512, 2) void fps_kernel(const float* __restrict__ ws,
                                                     float* __restrict__ out_xyz) {
    #pragma clang fp contract(off)
    const int b = blockIdx.x;
    const int tid = threadIdx.x;
    const int lane = tid & 63;
    const int wv = tid >> 6;
    const float4* p4 = (const float4*)(ws + WS_P4) + b * Nn;

    __shared__ unsigned long long sKey[2][8];
    __shared__ float sHist[Sn * 3];
    __shared__ float4 sBuf[2048];      // scatter staging (one quarter at a time)
    __shared__ int sH[256];            // histogram
    __shared__ int sC[256];            // running cursors (exclusive starts)

    // ---- load original points (coalesced) ----
    float4 t4[16];
    #pragma unroll
    for (int j = 0; j < 16; j++) t4[j] = p4[j * 512 + tid];

    // ---- histogram over 256 z-bins ----
    for (int i = tid; i < 256; i += 512) sH[i] = 0;
    __syncthreads();
    int slot[16];
    #pragma unroll
    for (int j = 0; j < 16; j++) {
        int bin = (int)(t4[j].z * 256.0f);
        bin = bin < 0 ? 0 : (bin > 255 ? 255 : bin);
        slot[j] = bin;                  // holds bin id for now
        atomicAdd(&sH[bin], 1);
    }
    __syncthreads();

    // ---- exclusive scan of 256 bins (wave 0, 4 bins/lane) ----
    if (tid < 64) {
        int b4 = tid * 4;
        int h0 = sH[b4], h1 = sH[b4 + 1], h2 = sH[b4 + 2], h3 = sH[b4 + 3];
        int sum = h0 + h1 + h2 + h3;
        int inc = sum;
        #pragma unroll
        for (int off = 1; off < 64; off <<= 1) {
            int o = __shfl_up(inc, off);
            if (tid >= off) inc += o;
        }
        int exc = inc - sum;
        sC[b4]     = exc;
        sC[b4 + 1] = exc + h0;
        sC[b4 + 2] = exc + h0 + h1;
        sC[b4 + 3] = exc + h0 + h1 + h2;
    }
    __syncthreads();

    // ---- claim unique sorted slots ----
    #pragma unroll
    for (int j = 0; j < 16; j++)
        slot[j] = atomicAdd(&sC[slot[j]], 1);

    // ---- 4 scatter rounds of 2048 slots each; waves 2r,2r+1 read round r ----
    float2v pX[8], pY[8], pZ[8], dI[8];
    unsigned oA[8], oB[8];
    for (int r = 0; r < 4; r++) {
        __syncthreads();
        int lo = r * 2048;
        #pragma unroll
        for (int j = 0; j < 16; j++) {
            int rel = slot[j] - lo;
            if ((unsigned)rel < 2048u)
                sBuf[rel] = make_float4(t4[j].x, t4[j].y, t4[j].z,
                                        __int_as_float(j * 512 + tid));
        }
        __syncthreads();
        if ((wv >> 1) == r) {
            int base = (wv & 1) * 1024 + lane * 2;
            #pragma unroll
            for (int u = 0; u < 8; u++) {
                float4 va = sBuf[base + u * 128];
                float4 vb = sBuf[base + u * 128 + 1];
                pX[u].x = va.x; pX[u].y = vb.x;
                pY[u].x = va.y; pY[u].y = vb.y;
                pZ[u].x = va.z; pZ[u].y = vb.z;
                oA[u] = (unsigned)__float_as_int(va.w);
                oB[u] = (unsigned)__float_as_int(vb.w);
                dI[u].x = 1e10f; dI[u].y = 1e10f;
            }
        }
    }
    __syncthreads();

    #pragma unroll
    for (int u = 0; u < 8; u++)
        asm volatile("" : "+v"(pX[u]), "+v"(pY[u]), "+v"(pZ[u]));

    // ---- wave z-bbox (exact min/max via full-lane butterfly, one time) ----
    float zl = fminf(pZ[0].x, pZ[0].y);
    float zh = fmaxf(pZ[0].x, pZ[0].y);
    #pragma unroll
    for (int u = 1; u < 8; u++) {
        zl = fminf(zl, fminf(pZ[u].x, pZ[u].y));
        zh = fmaxf(zh, fmaxf(pZ[u].x, pZ[u].y));
    }
    #pragma unroll
    for (int off = 1; off < 64; off <<= 1) {
        zl = fminf(zl, __shfl_xor(zl, off));
        zh = fmaxf(zh, __shfl_xor(zh, off));
    }

    // ---- main FPS loop ----
    float4 c0 = p4[0];
    float cx = c0.x, cy = c0.y, cz = c0.z;
    float wmaxC = 1e30f;     // cached wave max (forces first step active)
    unsigned bestC = 0u;     // cached wave argmax key (~origIdx)

    for (int s = 0; s < Sn; s++) {
        const int par = s & 1;
        if (tid == 0) {
            sHist[s * 3 + 0] = cx;
            sHist[s * 3 + 1] = cy;
            sHist[s * 3 + 2] = cz;
        }

        // conservative slab distance: skip only if provably no dist changes
        float dz = fmaxf(fmaxf(zl - cz, cz - zh), 0.0f);
        float dz2s = dz * dz * 0.999999f;
        if (dz2s < wmaxC) {   // wave-uniform branch
            float nxs = -cx, nys = -cy, nzs = -cz;
            float2v nX, nY, nZ;
            nX.x = nxs; nX.y = nxs;
            nY.x = nys; nY.y = nys;
            nZ.x = nzs; nZ.y = nzs;

            float lv = -1.0f;
            #pragma unroll
            for (int u = 0; u < 8; u++) {
                float2v dx, dy, dz_, xx, yy, zz, s1, d2;
                asm("v_pk_add_f32 %0, %1, %2" : "=v"(dx) : "v"(pX[u]), "v"(nX));
                asm("v_pk_add_f32 %0, %1, %2" : "=v"(dy) : "v"(pY[u]), "v"(nY));
                asm("v_pk_add_f32 %0, %1, %2" : "=v"(dz_) : "v"(pZ[u]), "v"(nZ));
                asm("v_pk_mul_f32 %0, %1, %1" : "=v"(xx) : "v"(dx));
                asm("v_pk_mul_f32 %0, %1, %1" : "=v"(yy) : "v"(dy));
                asm("v_pk_mul_f32 %0, %1, %1" : "=v"(zz) : "v"(dz_));
                asm("v_pk_add_f32 %0, %1, %2" : "=v"(s1) : "v"(xx), "v"(yy));
                asm("v_pk_add_f32 %0, %1, %2" : "=v"(d2) : "v"(s1), "v"(zz));
                float mx = fminf(dI[u].x, d2.x);
                float my = fminf(dI[u].y, d2.y);
                dI[u].x = mx; dI[u].y = my;
                lv = fmaxf(fmaxf(lv, mx), my);   // v_max3_f32
            }
            float wmax = wave_fmax_dpp(lv);

            unsigned c[16];
            #pragma unroll
            for (int u = 0; u < 8; u++) {
                c[2 * u]     = (dI[u].x == wmax) ? (0xFFFFFFFFu - oA[u]) : 0u;
                c[2 * u + 1] = (dI[u].y == wmax) ? (0xFFFFFFFFu - oB[u]) : 0u;
            }
            #pragma unroll
            for (int st = 1; st < 16; st <<= 1)
                #pragma unroll
                for (int i = 0; i < 16; i += 2 * st)
                    c[i] = (c[i + st] > c[i]) ? c[i + st] : c[i];
            unsigned best = wave_umax_dpp(c[0]);

            wmaxC = wmax;
            bestC = best;
        }

        if (lane == 0)
            sKey[par][wv] =
                ((unsigned long long)__float_as_uint(wmaxC) << 32) |
                (unsigned long long)bestC;
        __syncthreads();

        unsigned long long a0 = sKey[par][0], a1 = sKey[par][1];
        unsigned long long a2 = sKey[par][2], a3 = sKey[par][3];
        unsigned long long a4 = sKey[par][4], a5 = sKey[par][5];
        unsigned long long a6 = sKey[par][6], a7 = sKey[par][7];
        a0 = (a1 > a0) ? a1 : a0;
        a2 = (a3 > a2) ? a3 : a2;
        a4 = (a5 > a4) ? a5 : a4;
        a6 = (a7 > a6) ? a7 : a6;
        a0 = (a2 > a0) ? a2 : a0;
        a4 = (a6 > a4) ? a6 : a4;
        unsigned long long k = (a4 > a0) ? a4 : a0;

        int p = (int)(0xFFFFFFFFu - (unsigned)(k & 0xFFFFFFFFull));
        p = __builtin_amdgcn_readfirstlane(p);
        float4 c4 = p4[p];
        cx = c4.x; cy = c4.y; cz = c4.z;
    }

    __syncthreads();
    float4* o4 = (float4*)(out_xyz + b * Sn * 3);
    const float4* h4 = (const float4*)sHist;
    #pragma unroll
    for (int i = tid; i < Sn * 3 / 4; i += 512) o4[i] = h4[i];
}

// ---------------------------------------------------------------------------
// Ball query (unchanged; exact-decision verified: absmax 0.0).
// ---------------------------------------------------------------------------
__global__ __launch_bounds__(256) void ballq_kernel(const float* __restrict__ ws,
                                                    const float* __restrict__ newxyz,
                                                    int* __restrict__ grp) {
    #pragma clang fp contract(off)
    int t = blockIdx.x * 256 + threadIdx.x;
    int wid = t >> 6;
    int lane = t & 63;
    int b = wid >> 11;
    const float4* p4 = (const float4*)(ws + WS_P4) + b * Nn;

    float nx = newxyz[wid * 3 + 0], ny = newxyz[wid * 3 + 1], nz = newxyz[wid * 3 + 2];
    float a2 = (nx * nx + ny * ny) + nz * nz;

    int total = 0;
    int firstp = 0;
    for (int c = 0; c < Nn / 64; c++) {
        int p = c * 64 + lane;
        float4 v = p4[p];
        float x = v.x, y = v.y, z = v.z;
        float bv = (x * x + y * y) + z * z;
        float dot = __builtin_fmaf(nx, x, 0.0f);
        dot = __builtin_fmaf(ny, y, dot);
        dot = __builtin_fmaf(nz, z, dot);
        float sq = (a2 + bv) - 2.0f * dot;
        bool hit = !(sq > R2c);
        unsigned long long mask = __ballot(hit);
        if (mask) {
            if (total == 0) firstp = c * 64 + (__ffsll(mask) - 1);
            int rank = __popcll(mask & ((1ull << lane) - 1ull));
            int slot = total + rank;
            if (hit && slot < Kn) grp[wid * Kn + slot] = p;
            total += (int)__popcll(mask);
            if (total >= Kn) break;
        }
    }
    if (lane >= total && lane < Kn) grp[wid * Kn + lane] = firstp;
}

// ---------------------------------------------------------------------------
// MFMA MLP (unchanged): one group per block, 256 threads = 4 waves.
// ---------------------------------------------------------------------------
template<int KB, int O>
__device__ __forceinline__ void mfma_layer(const unsigned short* __restrict__ X,
                                           unsigned short* __restrict__ Y,
                                           const unsigned short* __restrict__ wb,
                                           const float* __restrict__ bias,
                                           int lane, int wv) {
    const int Cp = KB * 32;
    const int mt = wv & 1;
    const int mrow = mt * 16 + (lane & 15);
    const int quad = lane >> 4;

    short8 a[KB];
    #pragma unroll
    for (int kb = 0; kb < KB; kb++)
        a[kb] = *(const short8*)&X[mrow * HSTR + kb * 32 + quad * 8];

    for (int nt = (wv >> 1); nt < O / 16; nt += 2) {
        int n0 = nt * 16;
        float bv = bias[n0 + (lane & 15)];
        floatx4 acc = {bv, bv, bv, bv};
        #pragma unroll
        for (int kb = 0; kb < KB; kb++) {
            short8 bf = *(const short8*)&wb[(n0 + (lane & 15)) * Cp + kb * 32 + quad * 8];
            acc = __builtin_amdgcn_mfma_f32_16x16x32_bf16(a[kb], bf, acc, 0, 0, 0);
        }
        #pragma unroll
        for (int r = 0; r < 4; r++) {
            float v = fmaxf(acc[r], 0.f);
            int m = mt * 16 + quad * 4 + r;
            Y[m * HSTR + n0 + (lane & 15)] = f2bf(v);
        }
    }
}

__global__ __launch_bounds__(256) void mlp_kernel(const float* __restrict__ xyz,
                                                  const float* __restrict__ feat,
                                                  const float* __restrict__ ws,
                                                  const int* __restrict__ grp,
                                                  const float* __restrict__ b1,
                                                  const float* __restrict__ b2,
                                                  const float* __restrict__ b3,
                                                  float* __restrict__ out) {
    __shared__ __align__(16) unsigned short hA[32 * HSTR];
    __shared__ __align__(16) unsigned short hB[32 * HSTR];
    __shared__ float mxs[2][256];
    __shared__ int   sIdx[Kn];
    __shared__ float sCent[3];

    int g = blockIdx.x;            // b*S + s
    int b = g >> 11;
    int tid = threadIdx.x;
    int lane = tid & 63, wv = tid >> 6;

    if (tid < Kn) sIdx[tid] = grp[g * Kn + tid];
    if (tid == 0) { sCent[0] = out[g*3]; sCent[1] = out[g*3+1]; sCent[2] = out[g*3+2]; }
    // zero hA (pad cols must be 0 for the K=96 layer)
    {
        short8 z = {0,0,0,0,0,0,0,0};
        for (int i = tid; i < 32 * HSTR / 8; i += 256)
            ((short8*)hA)[i] = z;
    }
    __syncthreads();

    { // stage h0: feats -> cols 0..63 (bf16x8 vector writes), xyz -> 64..66
        int m = tid >> 3, m8 = tid & 7;
        int idx = sIdx[m];
        int base = b * Nn + idx;
        const float4* f4 = (const float4*)(feat + base * 64 + m8 * 8);
        float4 va = f4[0], vb = f4[1];
        short8 pk;
        pk[0] = (short)f2bf(va.x); pk[1] = (short)f2bf(va.y);
        pk[2] = (short)f2bf(va.z); pk[3] = (short)f2bf(va.w);
        pk[4] = (short)f2bf(vb.x); pk[5] = (short)f2bf(vb.y);
        pk[6] = (short)f2bf(vb.z); pk[7] = (short)f2bf(vb.w);
        *(short8*)&hA[m * HSTR + m8 * 8] = pk;
        if (m8 == 0) {
            hA[m * HSTR + 64] = f2bf(xyz[base * 3 + 0] - sCent[0]);
            hA[m * HSTR + 65] = f2bf(xyz[base * 3 + 1] - sCent[1]);
            hA[m * HSTR + 66] = f2bf(xyz[base * 3 + 2] - sCent[2]);
        }
    }
    __syncthreads();

    const unsigned short* wb1 = (const unsigned short*)(ws + WS_WB1);
    const unsigned short* wb2 = (const unsigned short*)(ws + WS_WB2);
    const unsigned short* wb3 = (const unsigned short*)(ws + WS_WB3);

    mfma_layer<3, 64>(hA, hB, wb1, b1, lane, wv);     // 96 -> 64
    __syncthreads();
    mfma_layer<2, 128>(hB, hA, wb2, b2, lane, wv);    // 64 -> 128
    __syncthreads();

    { // L3 (128 -> 256) + fused maxpool
        const int mt = wv & 1;
        const int mrow = mt * 16 + (lane & 15);
        const int quad = lane >> 4;
        short8 a[4];
        #pragma unroll
        for (int kb = 0; kb < 4; kb++)
            a[kb] = *(const short8*)&hA[mrow * HSTR + kb * 32 + quad * 8];
        for (int nt = (wv >> 1); nt < 16; nt += 2) {
            int n0 = nt * 16;
            float bv = b3[n0 + (lane & 15)];
            floatx4 acc = {bv, bv, bv, bv};
            #pragma unroll
            for (int kb = 0; kb < 4; kb++) {
                short8 bf = *(const short8*)&wb3[(n0 + (lane & 15)) * 128 + kb * 32 + quad * 8];
                acc = __builtin_amdgcn_mfma_f32_16x16x32_bf16(a[kb], bf, acc, 0, 0, 0);
            }
            float pm = fmaxf(fmaxf(fmaxf(acc[0], acc[1]), fmaxf(acc[2], acc[3])), 0.f);
            pm = fmaxf(pm, __shfl_xor(pm, 16));   // reduce across the 4 quads
            pm = fmaxf(pm, __shfl_xor(pm, 32));
            if (lane < 16) mxs[mt][n0 + lane] = pm;
        }
    }
    __syncthreads();

    out[OUT_XYZ + g * 256 + tid] = fmaxf(mxs[0][tid], mxs[1][tid]);
}

// ---------------------------------------------------------------------------
extern "C" void kernel_launch(void* const* d_in, const int* in_sizes, int n_in,
                              void* d_out, int out_size, void* d_ws, size_t ws_size,
                              hipStream_t stream) {
    const float* xyz  = (const float*)d_in[0];
    const float* feat = (const float*)d_in[1];
    const float* W1   = (const float*)d_in[2];
    const float* b1   = (const float*)d_in[3];
    const float* W2   = (const float*)d_in[4];
    const float* b2   = (const float*)d_in[5];
    const float* W3   = (const float*)d_in[6];
    const float* b3   = (const float*)d_in[7];
    float* out = (float*)d_out;
    float* ws  = (float*)d_ws;
    int*   grp = (int*)d_ws + WS_GRP;

    hipLaunchKernelGGL(prep_kernel, dim3(312), dim3(256), 0, stream, xyz, W1, W2, W3, ws);
    hipLaunchKernelGGL(fps_kernel, dim3(Bn), dim3(512), 0, stream, ws, out);
    hipLaunchKernelGGL(ballq_kernel, dim3(Bn * Sn / 4), dim3(256), 0, stream, ws, out, grp);
    hipLaunchKernelGGL(mlp_kernel, dim3(Bn * Sn), dim3(256), 0, stream,
                       xyz, feat, ws, grp, b1, b2, b3, out);
}

// Round 5
// 1804.560 us; speedup vs baseline: 1.9221x; 1.0345x over previous
//
#include <hip/hip_runtime.h>

// Problem constants
#define Bn 4
#define Nn 8192
#define Dn 64
#define Sn 2048
#define Kn 32
#define R2c 0.04f          // f32(0.2*0.2)
#define OUT_XYZ (Bn*Sn*3)  // 24576 floats of new_xyz, then feats

// Workspace layout (units = 4-byte elements)
#define WS_P4  0            // [B*N] float4 {x,y,z,0}
#define WS_WB1 131072       // bf16 W1' [64][96]  (feat-first permute, zero pad)
#define WS_WB2 134144       // bf16 W2  [128][64]
#define WS_WB3 138240       // bf16 W3  [256][128]
#define WS_GRP 154624       // int grp_idx [B*S][K]

#define HSTR 136            // bf16 LDS row stride (128 max C + 8 pad)

typedef __attribute__((ext_vector_type(8))) short short8;
typedef __attribute__((ext_vector_type(4))) float floatx4;
typedef __attribute__((ext_vector_type(2))) float float2v;
typedef unsigned long long ull;

// float -> bf16 (RNE) without relying on header APIs
__device__ __forceinline__ unsigned short f2bf(float f) {
    unsigned u = __float_as_uint(f);
    return (unsigned short)((u + 0x7FFFu + ((u >> 16) & 1u)) >> 16);
}

// ---------------------------------------------------------------------------
// Prep: xyz -> float4 array; weights -> bf16 [O][Cp] row-major.
// ---------------------------------------------------------------------------
__global__ __launch_bounds__(256) void prep_kernel(const float* __restrict__ xyz,
                                                   const float* __restrict__ W1,
                                                   const float* __restrict__ W2,
                                                   const float* __restrict__ W3,
                                                   float* __restrict__ ws) {
    int id = blockIdx.x * 256 + threadIdx.x;
    if (id < Bn * Nn) {
        float4* p4 = (float4*)(ws + WS_P4);
        p4[id] = make_float4(xyz[id * 3 + 0], xyz[id * 3 + 1], xyz[id * 3 + 2], 0.f);
    }
    int i1 = id - Bn * Nn;
    if (i1 >= 0 && i1 < 64 * 96) {
        int o = i1 / 96, c = i1 % 96;
        float v = (c < 64) ? W1[o * 67 + 3 + c] : (c < 67 ? W1[o * 67 + (c - 64)] : 0.f);
        ((unsigned short*)(ws + WS_WB1))[i1] = f2bf(v);
    }
    int i2 = i1 - 64 * 96;
    if (i2 >= 0 && i2 < 128 * 64)
        ((unsigned short*)(ws + WS_WB2))[i2] = f2bf(W2[i2]);
    int i3 = i2 - 128 * 64;
    if (i3 >= 0 && i3 < 256 * 128)
        ((unsigned short*)(ws + WS_WB3))[i3] = f2bf(W3[i3]);
}

// Fused wave-64 lexicographic max of 64-bit keys (hi=dist bits, lo=payload).
// One DPP ladder; 0-injection from bound_ctrl can never win (real keys have
// lo!=0 or hi!=0, and (0,0) loses any comparison it could steal).
// Result broadcast via 2 readlanes from lane 63.
__device__ __forceinline__ ull wave_kmax_dpp(ull k) {
    unsigned lo = (unsigned)k, hi = (unsigned)(k >> 32);
#define KRUNG(ctl)                                                                          \
    {                                                                                       \
        unsigned tlo = (unsigned)__builtin_amdgcn_update_dpp(0, (int)lo, ctl, 0xf, 0xf, true); \
        unsigned thi = (unsigned)__builtin_amdgcn_update_dpp(0, (int)hi, ctl, 0xf, 0xf, true); \
        ull t = ((ull)thi << 32) | tlo;                                                     \
        ull c = ((ull)hi << 32) | lo;                                                       \
        if (t > c) { hi = thi; lo = tlo; }                                                  \
    }
    KRUNG(0x111) KRUNG(0x112) KRUNG(0x114) KRUNG(0x118) KRUNG(0x142) KRUNG(0x143)
#undef KRUNG
    hi = (unsigned)__builtin_amdgcn_readlane((int)hi, 63);
    lo = (unsigned)__builtin_amdgcn_readlane((int)lo, 63);
    return ((ull)hi << 32) | lo;
}

// ---------------------------------------------------------------------------
// Farthest point sampling — sorted wave-skip + fused-tail version.
//
// Structure: 512 thr (8 waves) x 16 pts/thread. Prologue z-sorts the 8192
// points (256-bin counting sort) DIRECTLY into a 128KB LDS table sP4[8192]
// (x,y,z,origIdx); wave w owns sorted slots [w*1024,(w+1)*1024) in registers.
// Per-wave slab skip as R4 (bit-exact: skip implies min(dist,d)=dist for all
// slab points).
//
// Tail rework vs R4 (1595 us):
//  * ONE fused u64 ladder: key = (dist<<32) | ((8191-orig)<<13) | slot.
//    Lane: lv (max3 chain) -> lane-tie recovery tree (max lo among own ties)
//    -> single 6-rung lexicographic DPP ladder. Replaces the 3-phase
//    fmax-ladder -> recovery -> umax-ladder chain. Tie semantics identical:
//    max key == (max dist, min origIdx) since orig indices are distinct.
//  * winner coords via broadcast LDS read sP4[slot] (slot payload from the
//    winning key) — the per-step L2 fetch leaves the serial chain.
//  * centroid written straight to out_xyz per step (fire-and-forget store);
//    sHist LDS freed for the point table.
// ---------------------------------------------------------------------------
__global__ __launch_bounds__(512, 2) void fps_kernel(const float* __restrict__ ws,
                                                     float* __restrict__ out_xyz) {
    #pragma clang fp contract(off)
    const int b = blockIdx.x;
    const int tid = threadIdx.x;
    const int lane = tid & 63;
    const int wv = tid >> 6;
    const float4* p4 = (const float4*)(ws + WS_P4) + b * Nn;

    __shared__ __align__(16) float4 sP4[Nn];   // 128 KB sorted point table
    __shared__ ull sKey[2][8];
    __shared__ int sH[256];                    // histogram
    __shared__ int sC[256];                    // cursors (exclusive starts)

    // ---- load original points (coalesced) ----
    float4 t4[16];
    #pragma unroll
    for (int j = 0; j < 16; j++) t4[j] = p4[j * 512 + tid];

    // ---- histogram over 256 z-bins ----
    for (int i = tid; i < 256; i += 512) sH[i] = 0;
    __syncthreads();
    int slt[16];
    #pragma unroll
    for (int j = 0; j < 16; j++) {
        int bin = (int)(t4[j].z * 256.0f);
        bin = bin < 0 ? 0 : (bin > 255 ? 255 : bin);
        slt[j] = bin;
        atomicAdd(&sH[bin], 1);
    }
    __syncthreads();

    // ---- exclusive scan of 256 bins (wave 0, 4 bins/lane) ----
    if (tid < 64) {
        int b4 = tid * 4;
        int h0 = sH[b4], h1 = sH[b4 + 1], h2 = sH[b4 + 2], h3 = sH[b4 + 3];
        int sum = h0 + h1 + h2 + h3;
        int inc = sum;
        #pragma unroll
        for (int off = 1; off < 64; off <<= 1) {
            int o = __shfl_up(inc, off);
            if (tid >= off) inc += o;
        }
        int exc = inc - sum;
        sC[b4]     = exc;
        sC[b4 + 1] = exc + h0;
        sC[b4 + 2] = exc + h0 + h1;
        sC[b4 + 3] = exc + h0 + h1 + h2;
    }
    __syncthreads();

    // ---- claim unique sorted slots, scatter into the table ----
    #pragma unroll
    for (int j = 0; j < 16; j++)
        slt[j] = atomicAdd(&sC[slt[j]], 1);
    #pragma unroll
    for (int j = 0; j < 16; j++)
        sP4[slt[j]] = make_float4(t4[j].x, t4[j].y, t4[j].z,
                                  __int_as_float(j * 512 + tid));
    __syncthreads();

    // ---- slab read: wave wv owns slots [wv*1024, wv*1024+1024) ----
    float2v pX[8], pY[8], pZ[8], dI[8];
    unsigned loA[8], loB[8];
    const int sbase = wv * 1024 + lane * 2;
    #pragma unroll
    for (int u = 0; u < 8; u++) {
        int sa = sbase + u * 128;
        float4 va = sP4[sa];
        float4 vb = sP4[sa + 1];
        pX[u].x = va.x; pX[u].y = vb.x;
        pY[u].x = va.y; pY[u].y = vb.y;
        pZ[u].x = va.z; pZ[u].y = vb.z;
        unsigned ogA = (unsigned)__float_as_int(va.w);
        unsigned ogB = (unsigned)__float_as_int(vb.w);
        loA[u] = ((8191u - ogA) << 13) | (unsigned)sa;
        loB[u] = ((8191u - ogB) << 13) | (unsigned)(sa + 1);
        dI[u].x = 1e10f; dI[u].y = 1e10f;
    }
    #pragma unroll
    for (int u = 0; u < 8; u++)
        asm volatile("" : "+v"(pX[u]), "+v"(pY[u]), "+v"(pZ[u]));

    // ---- wave z-bbox (exact min/max butterfly, one time) ----
    float zl = fminf(pZ[0].x, pZ[0].y);
    float zh = fmaxf(pZ[0].x, pZ[0].y);
    #pragma unroll
    for (int u = 1; u < 8; u++) {
        zl = fminf(zl, fminf(pZ[u].x, pZ[u].y));
        zh = fmaxf(zh, fmaxf(pZ[u].x, pZ[u].y));
    }
    #pragma unroll
    for (int off = 1; off < 64; off <<= 1) {
        zl = fminf(zl, __shfl_xor(zl, off));
        zh = fmaxf(zh, __shfl_xor(zh, off));
    }

    // ---- main FPS loop ----
    float4 c0 = p4[0];
    float cx = c0.x, cy = c0.y, cz = c0.z;
    float wmaxC = 1e30f;     // cached wave max dist (forces first step active)
    ull bestK = 0;           // cached wave best key

    float* outc = out_xyz + b * Sn * 3;

    for (int s = 0; s < Sn; s++) {
        const int par = s & 1;
        if (tid == 0) {       // fire-and-forget sample record
            outc[s * 3 + 0] = cx;
            outc[s * 3 + 1] = cy;
            outc[s * 3 + 2] = cz;
        }

        // conservative slab distance: skip only if provably no dist changes
        float dzb = fmaxf(fmaxf(zl - cz, cz - zh), 0.0f);
        float dz2s = dzb * dzb * 0.999999f;
        if (dz2s < wmaxC) {   // wave-uniform branch
            float nxs = -cx, nys = -cy, nzs = -cz;
            float2v nX, nY, nZ;
            nX.x = nxs; nX.y = nxs;
            nY.x = nys; nY.y = nys;
            nZ.x = nzs; nZ.y = nzs;

            float lv = -1.0f;
            #pragma unroll
            for (int u = 0; u < 8; u++) {
                float2v dx, dy, dz_, xx, yy, zz, s1, d2;
                asm("v_pk_add_f32 %0, %1, %2" : "=v"(dx) : "v"(pX[u]), "v"(nX));
                asm("v_pk_add_f32 %0, %1, %2" : "=v"(dy) : "v"(pY[u]), "v"(nY));
                asm("v_pk_add_f32 %0, %1, %2" : "=v"(dz_) : "v"(pZ[u]), "v"(nZ));
                asm("v_pk_mul_f32 %0, %1, %1" : "=v"(xx) : "v"(dx));
                asm("v_pk_mul_f32 %0, %1, %1" : "=v"(yy) : "v"(dy));
                asm("v_pk_mul_f32 %0, %1, %1" : "=v"(zz) : "v"(dz_));
                asm("v_pk_add_f32 %0, %1, %2" : "=v"(s1) : "v"(xx), "v"(yy));
                asm("v_pk_add_f32 %0, %1, %2" : "=v"(d2) : "v"(s1), "v"(zz));
                float mx = fminf(dI[u].x, d2.x);
                float my = fminf(dI[u].y, d2.y);
                dI[u].x = mx; dI[u].y = my;
                lv = fmaxf(fmaxf(lv, mx), my);   // v_max3_f32
            }

            // lane-tie recovery: max lo among THIS lane's points at lv
            unsigned c[16];
            #pragma unroll
            for (int u = 0; u < 8; u++) {
                c[2 * u]     = (dI[u].x == lv) ? loA[u] : 0u;
                c[2 * u + 1] = (dI[u].y == lv) ? loB[u] : 0u;
            }
            #pragma unroll
            for (int st = 1; st < 16; st <<= 1)
                #pragma unroll
                for (int i = 0; i < 16; i += 2 * st)
                    c[i] = (c[i + st] > c[i]) ? c[i + st] : c[i];

            // fused lexicographic wave reduce
            ull k = ((ull)__float_as_uint(lv) << 32) | (ull)c[0];
            bestK = wave_kmax_dpp(k);
            wmaxC = __uint_as_float((unsigned)(bestK >> 32));
        }

        if (lane == 0) sKey[par][wv] = bestK;
        __syncthreads();

        ull a0 = sKey[par][0], a1 = sKey[par][1];
        ull a2 = sKey[par][2], a3 = sKey[par][3];
        ull a4 = sKey[par][4], a5 = sKey[par][5];
        ull a6 = sKey[par][6], a7 = sKey[par][7];
        a0 = (a1 > a0) ? a1 : a0;
        a2 = (a3 > a2) ? a3 : a2;
        a4 = (a5 > a4) ? a5 : a4;
        a6 = (a7 > a6) ? a7 : a6;
        a0 = (a2 > a0) ? a2 : a0;
        a4 = (a6 > a4) ? a6 : a4;
        ull kk = (a4 > a0) ? a4 : a0;

        // winner coords: broadcast LDS read via slot payload
        int slot = (int)(kk & 0x1FFFull);
        float4 c4 = sP4[slot];
        cx = c4.x; cy = c4.y; cz = c4.z;
    }
}

// ---------------------------------------------------------------------------
// Ball query (unchanged; exact-decision verified: absmax 0.0).
// ---------------------------------------------------------------------------
__global__ __launch_bounds__(256) void ballq_kernel(const float* __restrict__ ws,
                                                    const float* __restrict__ newxyz,
                                                    int* __restrict__ grp) {
    #pragma clang fp contract(off)
    int t = blockIdx.x * 256 + threadIdx.x;
    int wid = t >> 6;
    int lane = t & 63;
    int b = wid >> 11;
    const float4* p4 = (const float4*)(ws + WS_P4) + b * Nn;

    float nx = newxyz[wid * 3 + 0], ny = newxyz[wid * 3 + 1], nz = newxyz[wid * 3 + 2];
    float a2 = (nx * nx + ny * ny) + nz * nz;

    int total = 0;
    int firstp = 0;
    for (int c = 0; c < Nn / 64; c++) {
        int p = c * 64 + lane;
        float4 v = p4[p];
        float x = v.x, y = v.y, z = v.z;
        float bv = (x * x + y * y) + z * z;
        float dot = __builtin_fmaf(nx, x, 0.0f);
        dot = __builtin_fmaf(ny, y, dot);
        dot = __builtin_fmaf(nz, z, dot);
        float sq = (a2 + bv) - 2.0f * dot;
        bool hit = !(sq > R2c);
        unsigned long long mask = __ballot(hit);
        if (mask) {
            if (total == 0) firstp = c * 64 + (__ffsll(mask) - 1);
            int rank = __popcll(mask & ((1ull << lane) - 1ull));
            int slot = total + rank;
            if (hit && slot < Kn) grp[wid * Kn + slot] = p;
            total += (int)__popcll(mask);
            if (total >= Kn) break;
        }
    }
    if (lane >= total && lane < Kn) grp[wid * Kn + lane] = firstp;
}

// ---------------------------------------------------------------------------
// MFMA MLP (unchanged): one group per block, 256 threads = 4 waves.
// ---------------------------------------------------------------------------
template<int KB, int O>
__device__ __forceinline__ void mfma_layer(const unsigned short* __restrict__ X,
                                           unsigned short* __restrict__ Y,
                                           const unsigned short* __restrict__ wb,
                                           const float* __restrict__ bias,
                                           int lane, int wv) {
    const int Cp = KB * 32;
    const int mt = wv & 1;
    const int mrow = mt * 16 + (lane & 15);
    const int quad = lane >> 4;

    short8 a[KB];
    #pragma unroll
    for (int kb = 0; kb < KB; kb++)
        a[kb] = *(const short8*)&X[mrow * HSTR + kb * 32 + quad * 8];

    for (int nt = (wv >> 1); nt < O / 16; nt += 2) {
        int n0 = nt * 16;
        float bv = bias[n0 + (lane & 15)];
        floatx4 acc = {bv, bv, bv, bv};
        #pragma unroll
        for (int kb = 0; kb < KB; kb++) {
            short8 bf = *(const short8*)&wb[(n0 + (lane & 15)) * Cp + kb * 32 + quad * 8];
            acc = __builtin_amdgcn_mfma_f32_16x16x32_bf16(a[kb], bf, acc, 0, 0, 0);
        }
        #pragma unroll
        for (int r = 0; r < 4; r++) {
            float v = fmaxf(acc[r], 0.f);
            int m = mt * 16 + quad * 4 + r;
            Y[m * HSTR + n0 + (lane & 15)] = f2bf(v);
        }
    }
}

__global__ __launch_bounds__(256) void mlp_kernel(const float* __restrict__ xyz,
                                                  const float* __restrict__ feat,
                                                  const float* __restrict__ ws,
                                                  const int* __restrict__ grp,
                                                  const float* __restrict__ b1,
                                                  const float* __restrict__ b2,
                                                  const float* __restrict__ b3,
                                                  float* __restrict__ out) {
    __shared__ __align__(16) unsigned short hA[32 * HSTR];
    __shared__ __align__(16) unsigned short hB[32 * HSTR];
    __shared__ float mxs[2][256];
    __shared__ int   sIdx[Kn];
    __shared__ float sCent[3];

    int g = blockIdx.x;            // b*S + s
    int b = g >> 11;
    int tid = threadIdx.x;
    int lane = tid & 63, wv = tid >> 6;

    if (tid < Kn) sIdx[tid] = grp[g * Kn + tid];
    if (tid == 0) { sCent[0] = out[g*3]; sCent[1] = out[g*3+1]; sCent[2] = out[g*3+2]; }
    // zero hA (pad cols must be 0 for the K=96 layer)
    {
        short8 z = {0,0,0,0,0,0,0,0};
        for (int i = tid; i < 32 * HSTR / 8; i += 256)
            ((short8*)hA)[i] = z;
    }
    __syncthreads();

    { // stage h0: feats -> cols 0..63 (bf16x8 vector writes), xyz -> 64..66
        int m = tid >> 3, m8 = tid & 7;
        int idx = sIdx[m];
        int base = b * Nn + idx;
        const float4* f4 = (const float4*)(feat + base * 64 + m8 * 8);
        float4 va = f4[0], vb = f4[1];
        short8 pk;
        pk[0] = (short)f2bf(va.x); pk[1] = (short)f2bf(va.y);
        pk[2] = (short)f2bf(va.z); pk[3] = (short)f2bf(va.w);
        pk[4] = (short)f2bf(vb.x); pk[5] = (short)f2bf(vb.y);
        pk[6] = (short)f2bf(vb.z); pk[7] = (short)f2bf(vb.w);
        *(short8*)&hA[m * HSTR + m8 * 8] = pk;
        if (m8 == 0) {
            hA[m * HSTR + 64] = f2bf(xyz[base * 3 + 0] - sCent[0]);
            hA[m * HSTR + 65] = f2bf(xyz[base * 3 + 1] - sCent[1]);
            hA[m * HSTR + 66] = f2bf(xyz[base * 3 + 2] - sCent[2]);
        }
    }
    __syncthreads();

    const unsigned short* wb1 = (const unsigned short*)(ws + WS_WB1);
    const unsigned short* wb2 = (const unsigned short*)(ws + WS_WB2);
    const unsigned short* wb3 = (const unsigned short*)(ws + WS_WB3);

    mfma_layer<3, 64>(hA, hB, wb1, b1, lane, wv);     // 96 -> 64
    __syncthreads();
    mfma_layer<2, 128>(hB, hA, wb2, b2, lane, wv);    // 64 -> 128
    __syncthreads();

    { // L3 (128 -> 256) + fused maxpool
        const int mt = wv & 1;
        const int mrow = mt * 16 + (lane & 15);
        const int quad = lane >> 4;
        short8 a[4];
        #pragma unroll
        for (int kb = 0; kb < 4; kb++)
            a[kb] = *(const short8*)&hA[mrow * HSTR + kb * 32 + quad * 8];
        for (int nt = (wv >> 1); nt < 16; nt += 2) {
            int n0 = nt * 16;
            float bv = b3[n0 + (lane & 15)];
            floatx4 acc = {bv, bv, bv, bv};
            #pragma unroll
            for (int kb = 0; kb < 4; kb++) {
                short8 bf = *(const short8*)&wb3[(n0 + (lane & 15)) * 128 + kb * 32 + quad * 8];
                acc = __builtin_amdgcn_mfma_f32_16x16x32_bf16(a[kb], bf, acc, 0, 0, 0);
            }
            float pm = fmaxf(fmaxf(fmaxf(acc[0], acc[1]), fmaxf(acc[2], acc[3])), 0.f);
            pm = fmaxf(pm, __shfl_xor(pm, 16));   // reduce across the 4 quads
            pm = fmaxf(pm, __shfl_xor(pm, 32));
            if (lane < 16) mxs[mt][n0 + lane] = pm;
        }
    }
    __syncthreads();

    out[OUT_XYZ + g * 256 + tid] = fmaxf(mxs[0][tid], mxs[1][tid]);
}

// ---------------------------------------------------------------------------
extern "C" void kernel_launch(void* const* d_in, const int* in_sizes, int n_in,
                              void* d_out, int out_size, void* d_ws, size_t ws_size,
                              hipStream_t stream) {
    const float* xyz  = (const float*)d_in[0];
    const float* feat = (const float*)d_in[1];
    const float* W1   = (const float*)d_in[2];
    const float* b1   = (const float*)d_in[3];
    const float* W2   = (const float*)d_in[4];
    const float* b2   = (const float*)d_in[5];
    const float* W3   = (const float*)d_in[6];
    const float* b3   = (const float*)d_in[7];
    float* out = (float*)d_out;
    float* ws  = (float*)d_ws;
    int*   grp = (int*)d_ws + WS_GRP;

    hipLaunchKernelGGL(prep_kernel, dim3(312), dim3(256), 0, stream, xyz, W1, W2, W3, ws);
    hipLaunchKernelGGL(fps_kernel, dim3(Bn), dim3(512), 0, stream, ws, out);
    hipLaunchKernelGGL(ballq_kernel, dim3(Bn * Sn / 4), dim3(256), 0, stream, ws, out, grp);
    hipLaunchKernelGGL(mlp_kernel, dim3(Bn * Sn), dim3(256), 0, stream,
                       xyz, feat, ws, grp, b1, b2, b3, out);
}